// Round 11
// baseline (136.691 us; speedup 1.0000x reference)
//
#include <hip/hip_runtime.h>
#include <stdint.h>

#define N_REAL 500
#define NPAD   512
#define K_IN   3072
#define NBATCH 8192
#define NOUT   10
#define RADIUS 20.0f
#define VOLF   100.0f

typedef __attribute__((ext_vector_type(8))) __bf16 bf16x8;
typedef __attribute__((ext_vector_type(4))) float  f32x4;
typedef __attribute__((ext_vector_type(4))) unsigned short us4;

__device__ __forceinline__ unsigned short f2bf(float f) {
    unsigned int u = __float_as_uint(f);
    u += 0x7FFFu + ((u >> 16) & 1u);           // round-to-nearest-even
    return (unsigned short)(u >> 16);
}
__device__ __forceinline__ float bf2f(unsigned short h) {
    return __uint_as_float(((unsigned int)h) << 16);
}
// HW packed f32->bf16 (RNE), 2 insts per float4
__device__ __forceinline__ uint2 cvt_pk4(float4 v) {
    uint2 r;
    asm("v_cvt_pk_bf16_f32 %0, %1, %2" : "=v"(r.x) : "v"(v.x), "v"(v.y));
    asm("v_cvt_pk_bf16_f32 %0, %1, %2" : "=v"(r.y) : "v"(v.z), "v"(v.w));
    return r;
}

#define GLOBAL_AS __attribute__((address_space(1)))
#define LDS_AS    __attribute__((address_space(3)))
__device__ __forceinline__ void glds16(const void* g, void* l) {
    __builtin_amdgcn_global_load_lds((const GLOBAL_AS void*)g, (LDS_AS void*)l, 16, 0, 0);
}

// ---------------- prep1 ----------------
__global__ void prep1(const float* __restrict__ positions,
                      const float* __restrict__ features,
                      const float* __restrict__ out_w,
                      const float* __restrict__ biases,
                      float* __restrict__ feat_norm,   // [512][64]
                      float* __restrict__ pos_c,       // [512][4]
                      float* __restrict__ inw,         // [512]
                      float* __restrict__ biasp,       // [512]
                      float* __restrict__ wout)        // [512][10]
{
    int n = threadIdx.x;  // 512 threads, 1 block
    float e_in = 0.f, e_out = 0.f;
    float px = 0.f, py = 0.f, pz = 0.f;
    if (n < N_REAL) {
        px = fminf(fmaxf(positions[n*3+0], 0.1f), VOLF - 0.1f);
        py = fminf(fmaxf(positions[n*3+1], 0.1f), VOLF - 0.1f);
        pz = fminf(fmaxf(positions[n*3+2], 0.1f), VOLF - 0.1f);
        float xn = px / VOLF;
        e_in  = expf(-2.f * xn);
        e_out = expf(2.f * (xn - 1.f));
        float ss = 0.f;
        for (int f = 0; f < 64; ++f) { float v = features[n*64+f]; ss += v*v; }
        float nm = fmaxf(sqrtf(ss), 1e-6f);
        for (int f = 0; f < 64; ++f) feat_norm[n*64+f] = features[n*64+f] / nm;
    } else {
        for (int f = 0; f < 64; ++f) feat_norm[n*64+f] = 0.f;
    }
    pos_c[n*4+0] = px; pos_c[n*4+1] = py; pos_c[n*4+2] = pz; pos_c[n*4+3] = 0.f;

    __shared__ float s_in[512], s_out[512];
    s_in[n] = e_in; s_out[n] = e_out;
    __syncthreads();
    for (int s = 256; s > 0; s >>= 1) {
        if (n < s) { s_in[n] += s_in[n+s]; s_out[n] += s_out[n+s]; }
        __syncthreads();
    }
    float sum_in  = s_in[0]  + 1e-6f;
    float sum_out = s_out[0] + 1e-6f;

    inw[n]   = (n < N_REAL) ? (e_in / sum_in) : 0.f;
    biasp[n] = (n < N_REAL) ? biases[n] : 0.f;
    float wo = (n < N_REAL) ? (e_out / sum_out) : 0.f;
    for (int o = 0; o < NOUT; ++o)
        wout[n*NOUT + o] = (n < N_REAL) ? out_w[n*NOUT + o] * wo : 0.f;
}

// ---------------- prep2 ----------------
__global__ void prep2(const float* __restrict__ pos_c,
                      const float* __restrict__ feat_norm,
                      unsigned short* __restrict__ conn_w)   // [512][512] bf16
{
    int i = blockIdx.x;   // 512
    int t = threadIdx.x;  // 128
    __shared__ float fi[64];
    __shared__ float spos[4];
    __shared__ float red[128];
    if (t < 64) fi[t] = feat_norm[i*64 + t];
    if (t < 4)  spos[t] = pos_c[i*4 + t];
    __syncthreads();

    float w[4];
    float part = 0.f;
    for (int jj = 0; jj < 4; ++jj) {
        int j = t + jj*128;
        float val = 0.f;
        if (i < N_REAL && j < N_REAL) {
            float dx = spos[0] - pos_c[j*4+0];
            float dy = spos[1] - pos_c[j*4+1];
            float dz = spos[2] - pos_c[j*4+2];
            float sq = dx*dx + dy*dy + dz*dz;
            if (sq > 0.f) {
                float dist = sqrtf(sq);
                if (dist < RADIUS) {
                    float att = expf(-dist / RADIUS);
                    float sim = 0.f;
                    const float4* fj = (const float4*)(feat_norm + j*64);
                    const float4* fi4 = (const float4*)fi;
                    #pragma unroll
                    for (int f = 0; f < 16; ++f) {
                        float4 a = fi4[f]; float4 b = fj[f];
                        sim += a.x*b.x + a.y*b.y + a.z*b.z + a.w*b.w;
                    }
                    sim = fminf(fmaxf(sim, -1.f), 1.f);
                    val = att * (0.5f + 0.5f*sim);
                }
            }
        }
        w[jj] = val; part += val;
    }
    red[t] = part;
    __syncthreads();
    for (int s = 64; s > 0; s >>= 1) {
        if (t < s) red[t] += red[t+s];
        __syncthreads();
    }
    float inv = 1.f / (red[0] + 1e-6f);
    for (int jj = 0; jj < 4; ++jj)
        conn_w[(long)i*NPAD + t + jj*128] = f2bf(w[jj] * inv);
}

// ---------------- cast/pad f32 -> bf16 ----------------
__global__ void cast_pad(const float* __restrict__ src, unsigned short* __restrict__ dst,
                         long total_q, long src_q)
{
    long i = (long)blockIdx.x * blockDim.x + threadIdx.x;
    long stride = (long)gridDim.x * blockDim.x;
    for (; i < total_q; i += stride) {
        us4 o;
        if (i < src_q) {
            float4 v = ((const float4*)src)[i];
            o[0] = f2bf(v.x); o[1] = f2bf(v.y); o[2] = f2bf(v.z); o[3] = f2bf(v.w);
        } else {
            o[0] = 0; o[1] = 0; o[2] = 0; o[3] = 0;
        }
        ((us4*)dst)[i] = o;
    }
}

// gemm1 block map: 1024 blocks = 8 XCD x (8 m-panels x 4 n x 4 ks).
// The 4 n-blocks of one (m-panel, ks) share the same 393KB x-panel -> XCD L2.
__device__ __forceinline__ void block_map_g1(int b, int& m0, int& n0, int& ks) {
    int xcd = b & 7, loc = b >> 3;          // loc 0..127
    m0 = (xcd*8 + (loc >> 4)) * 128;
    int rest = loc & 15;
    n0 = (rest & 3) * 128;
    ks = rest >> 2;
}
// 512-block map (gemm2): 128 m-panels x 4 n-quarters.
__device__ __forceinline__ void block_map_g2(int b, int& m0, int& n0) {
    int xcd = b & 7, loc = b >> 3;          // loc 0..63
    m0 = (xcd*16 + (loc >> 2)) * 64;
    n0 = (loc & 3) * 128;
}

// ======== GEMM1 split-K4: tile 128x128, BK=64, strict single-buffer (m97 geometry).
// 64 FLOP per staged byte (2x the 64-dim tiles) -> staged-byte cap gives ~2x speedup.
// grid 1024 = 256 spatial x 4 K-splits of 768. Writes raw f32 partials.
__global__ __launch_bounds__(256, 4)
void gemm1s(const float* __restrict__ X,            // [8192][3072] f32
            const unsigned short* __restrict__ B,   // [512][3072] bf16
            float* __restrict__ Pf)                 // [4][8192][512] f32 partials
{
    __shared__ unsigned short As[128*64];  // 16 KiB, swizzled
    __shared__ unsigned short Bs[128*64];  // 16 KiB, swizzled

    const int tid  = threadIdx.x;
    const int lane = tid & 63;
    const int wave = tid >> 6;
    int m0, n0, ks; block_map_g1(blockIdx.x, m0, n0, ks);
    const int kbase = ks * (K_IN/4);          // 768
    const int wm = (wave >> 1) * 64;
    const int wn = (wave & 1) * 64;

    f32x4 acc[4][4];
    #pragma unroll
    for (int i = 0; i < 4; ++i)
        #pragma unroll
        for (int j = 0; j < 4; ++j)
            acc[i][j] = (f32x4){0.f,0.f,0.f,0.f};

    // A reg-staging: 128 rows x 16 float4 = 2048 f4, 8 per thread
    const float4* gA[8]; int lAo[8];
    #pragma unroll
    for (int s = 0; s < 8; ++s) {
        int f = tid + s*256;
        int row = f >> 4, c4 = f & 15;
        gA[s] = (const float4*)(X + (long)(m0 + row) * K_IN + kbase) + c4;
        lAo[s] = row*128 + ((c4*8) ^ ((row & 7) << 4));
    }
    // B: 16 KB = 4 glds16/thread, pre-swizzled global source
    const char* gB[4]; char* lB[4];
    #pragma unroll
    for (int s = 0; s < 4; ++s) {
        int o = tid*16 + s*4096;
        int row = o >> 7, d = o & 127;
        gB[s] = (const char*)B + (long)(n0 + row) * (K_IN*2) + kbase*2 + (d ^ ((row & 7) << 4));
        lB[s] = (char*)Bs + o;
    }

    for (int t = 0; t < 12; ++t) {
        __syncthreads();
        // issue: A first half, B glds, A second half (named halves, rule #20 safe)
        float4 va[4], vb4[4];
        #pragma unroll
        for (int s = 0; s < 4; ++s) { va[s] = gA[s][0]; gA[s] += 16; }
        #pragma unroll
        for (int s = 0; s < 4; ++s) { glds16(gB[s], lB[s]); gB[s] += 128; }
        #pragma unroll
        for (int s = 4; s < 8; ++s) { vb4[s-4] = gA[s][0]; gA[s] += 16; }
        #pragma unroll
        for (int s = 0; s < 4; ++s)
            *(uint2*)((char*)As + lAo[s]) = cvt_pk4(va[s]);
        #pragma unroll
        for (int s = 4; s < 8; ++s)
            *(uint2*)((char*)As + lAo[s]) = cvt_pk4(vb4[s-4]);
        asm volatile("s_waitcnt vmcnt(0) lgkmcnt(0)" ::: "memory");
        __syncthreads();

        #pragma unroll
        for (int kk = 0; kk < 2; ++kk) {
            const int cb = kk*64 + (lane >> 4) * 16;
            bf16x8 afr[4], bfr[4];
            #pragma unroll
            for (int i = 0; i < 4; ++i) {
                int r = wm + i*16 + (lane & 15);
                afr[i] = *(const bf16x8*)((const char*)As + r*128 + (cb ^ ((r & 7) << 4)));
            }
            #pragma unroll
            for (int j = 0; j < 4; ++j) {
                int r = wn + j*16 + (lane & 15);
                bfr[j] = *(const bf16x8*)((const char*)Bs + r*128 + (cb ^ ((r & 7) << 4)));
            }
            #pragma unroll
            for (int i = 0; i < 4; ++i)
                #pragma unroll
                for (int j = 0; j < 4; ++j)
                    acc[i][j] = __builtin_amdgcn_mfma_f32_16x16x32_bf16(afr[i], bfr[j], acc[i][j], 0, 0, 0);
        }
    }

    // raw f32 partial store
    float* P = Pf + (long)ks * (NBATCH * (long)NPAD);
    const int mbase = m0 + wm + (lane >> 4) * 4;
    const int nbase = n0 + wn + (lane & 15);
    #pragma unroll
    for (int j = 0; j < 4; ++j) {
        const int n = nbase + j*16;
        #pragma unroll
        for (int i = 0; i < 4; ++i)
            #pragma unroll
            for (int r = 0; r < 4; ++r) {
                const long m = mbase + i*16 + r;
                P[m*NPAD + n] = acc[i][j][r];
            }
    }
}

// ---- reduce 4 partials (fixed order) + input-gate epilogue -> act bf16 ----
__global__ __launch_bounds__(256)
void reduce_ep(const float* __restrict__ Pf,       // [4][8192][512] f32
               const float* __restrict__ inw,
               const float* __restrict__ biasp,
               unsigned short* __restrict__ act)   // [8192][512] bf16
{
    const long TOTQ = (long)NBATCH * NPAD / 4;     // 1,048,576 float4
    long i = (long)blockIdx.x * blockDim.x + threadIdx.x;
    long stride = (long)gridDim.x * blockDim.x;
    for (; i < TOTQ; i += stride) {
        float4 a = ((const float4*)Pf)[i];
        float4 b = ((const float4*)Pf)[i + TOTQ];
        float4 c = ((const float4*)Pf)[i + 2*TOTQ];
        float4 d = ((const float4*)Pf)[i + 3*TOTQ];
        int nq = (int)(i & 127);                   // (n/4) index
        float4 w  = ((const float4*)inw)[nq];
        float4 bi = ((const float4*)biasp)[nq];
        us4 o;
        o[0] = f2bf((((a.x + b.x) + c.x) + d.x) * w.x + bi.x);
        o[1] = f2bf((((a.y + b.y) + c.y) + d.y) * w.y + bi.y);
        o[2] = f2bf((((a.z + b.z) + c.z) + d.z) * w.z + bi.z);
        o[3] = f2bf((((a.w + b.w) + c.w) + d.w) * w.w + bi.w);
        ((us4*)act)[i] = o;
    }
}

// ======== GEMM2 (r8/r10-proven): BM=64, BN=128, BK=64, 3-buffer ring, depth-2. ========
__global__ __launch_bounds__(256, 4)
void gemm2_pipe(const unsigned short* __restrict__ A,      // act [8192][512] bf16
                const unsigned short* __restrict__ B,      // connw [512][512] bf16
                unsigned short* __restrict__ Cbf,          // [8192][512] bf16
                const unsigned short* __restrict__ actOld) // == A
{
    constexpr int ABUF = 8192;    // 64 x 64 bf16
    constexpr int BBUF = 16384;   // 128 x 64 bf16
    __shared__ __align__(16) char lds[3*(ABUF+BBUF)];  // 72 KB
    char* const Abase = lds;
    char* const Bbase = lds + 3*ABUF;

    const int tid  = threadIdx.x;
    const int lane = tid & 63;
    const int wave = tid >> 6;
    int m0, n0; block_map_g2(blockIdx.x, m0, n0);
    const int wm = (wave >> 1) * 32;
    const int wn = (wave & 1) * 64;

    f32x4 acc[2][4];
    #pragma unroll
    for (int i = 0; i < 2; ++i)
        #pragma unroll
        for (int j = 0; j < 4; ++j)
            acc[i][j] = (f32x4){0.f,0.f,0.f,0.f};

    const char* gB[4]; int lBo[4];
    #pragma unroll
    for (int s = 0; s < 4; ++s) {
        int o = tid*16 + s*4096;
        int row = o >> 7, d = o & 127;
        gB[s] = (const char*)B + (long)(n0 + row) * (NPAD*2) + (d ^ ((row & 7) << 4));
        lBo[s] = o;
    }
    const char* gA1[2]; int lAo1[2];
    #pragma unroll
    for (int s = 0; s < 2; ++s) {
        int o = tid*16 + s*4096;
        int row = o >> 7, d = o & 127;
        gA1[s] = (const char*)A + (long)(m0 + row) * (NPAD*2) + (d ^ ((row & 7) << 4));
        lAo1[s] = o;
    }

    const int NT = NPAD >> 6;   // 8

    // prologue: tiles 0,1 in flight
    #pragma unroll
    for (int s = 0; s < 2; ++s) { glds16(gA1[s], Abase + 0*ABUF + lAo1[s]); gA1[s] += 128; }
    #pragma unroll
    for (int s = 0; s < 4; ++s) { glds16(gB[s], Bbase + 0*BBUF + lBo[s]); gB[s] += 128; }
    #pragma unroll
    for (int s = 0; s < 2; ++s) { glds16(gA1[s], Abase + 1*ABUF + lAo1[s]); gA1[s] += 128; }
    #pragma unroll
    for (int s = 0; s < 4; ++s) { glds16(gB[s], Bbase + 1*BBUF + lBo[s]); gB[s] += 128; }

    int cur = 0;
    for (int t = 0; t < NT; ++t) {
        int fb = cur + 2; if (fb >= 3) fb -= 3;
        const bool more2 = (t + 2 < NT);
        const bool more1 = (t + 1 < NT);
        if (more2) {
            #pragma unroll
            for (int s = 0; s < 2; ++s) { glds16(gA1[s], Abase + fb*ABUF + lAo1[s]); gA1[s] += 128; }
            #pragma unroll
            for (int s = 0; s < 4; ++s) { glds16(gB[s], Bbase + fb*BBUF + lBo[s]); gB[s] += 128; }
            asm volatile("s_waitcnt vmcnt(12)" ::: "memory");
        } else if (more1) {
            asm volatile("s_waitcnt vmcnt(6)" ::: "memory");
        } else {
            asm volatile("s_waitcnt vmcnt(0)" ::: "memory");
        }
        __builtin_amdgcn_s_barrier();

        const char* Ab = Abase + cur*ABUF;
        const char* Bb = Bbase + cur*BBUF;
        #pragma unroll
        for (int kk = 0; kk < 2; ++kk) {
            const int cb = kk*64 + (lane >> 4) * 16;
            bf16x8 afr[2], bfr[4];
            #pragma unroll
            for (int i = 0; i < 2; ++i) {
                int r = wm + i*16 + (lane & 15);
                afr[i] = *(const bf16x8*)(Ab + r*128 + (cb ^ ((r & 7) << 4)));
            }
            #pragma unroll
            for (int j = 0; j < 4; ++j) {
                int r = wn + j*16 + (lane & 15);
                bfr[j] = *(const bf16x8*)(Bb + r*128 + (cb ^ ((r & 7) << 4)));
            }
            #pragma unroll
            for (int i = 0; i < 2; ++i)
                #pragma unroll
                for (int j = 0; j < 4; ++j)
                    acc[i][j] = __builtin_amdgcn_mfma_f32_16x16x32_bf16(afr[i], bfr[j], acc[i][j], 0, 0, 0);
        }
        __builtin_amdgcn_s_barrier();
        cur = (cur == 2) ? 0 : cur + 1;
    }

    const int mbase = m0 + wm + (lane >> 4) * 4;
    const int nbase = n0 + wn + (lane & 15);
    #pragma unroll
    for (int j = 0; j < 4; ++j) {
        const int n = nbase + j*16;
        #pragma unroll
        for (int i = 0; i < 2; ++i)
            #pragma unroll
            for (int r = 0; r < 4; ++r) {
                const long m = mbase + i*16 + r;
                float old = bf2f(actOld[m*NPAD + n]);
                float vv = fminf(fmaxf(old + 0.5f * acc[i][j][r], 0.f), 50.f);
                Cbf[m*NPAD + n] = f2bf(vv);
            }
    }
}

// ---------------- final projection: out[8192][10] = act @ wout ----------------
__global__ __launch_bounds__(256)
void out_gemm(const unsigned short* __restrict__ act,  // [8192][512] bf16
              const float* __restrict__ wout,          // [512][10]
              float* __restrict__ out)                 // [8192][10]
{
    __shared__ float sw[NPAD * NOUT];
    const int tid = threadIdx.x;
    for (int i = tid; i < NPAD*NOUT; i += 256) sw[i] = wout[i];
    __syncthreads();

    const int lane = tid & 63;
    const int wv   = tid >> 6;
    const int row  = blockIdx.x * 4 + wv;

    const unsigned short* ap = act + (long)row * NPAD + lane * 8;
    us4 v0 = *(const us4*)(ap);
    us4 v1 = *(const us4*)(ap + 4);

    float p[NOUT];
    #pragma unroll
    for (int o = 0; o < NOUT; ++o) p[o] = 0.f;

    const int nb = lane * 8;
    #pragma unroll
    for (int e = 0; e < 8; ++e) {
        float a = bf2f(e < 4 ? v0[e] : v1[e-4]);
        const float* wr = &sw[(nb + e) * NOUT];
        #pragma unroll
        for (int o = 0; o < NOUT; ++o) p[o] += a * wr[o];
    }
    #pragma unroll
    for (int o = 0; o < NOUT; ++o) {
        float s = p[o];
        for (int d = 32; d > 0; d >>= 1) s += __shfl_down(s, d);
        if (lane == 0) out[(long)row * NOUT + o] = s;
    }
}

extern "C" void kernel_launch(void* const* d_in, const int* in_sizes, int n_in,
                              void* d_out, int out_size, void* d_ws, size_t ws_size,
                              hipStream_t stream)
{
    const float* x        = (const float*)d_in[0];
    const float* pos      = (const float*)d_in[1];
    const float* in_w     = (const float*)d_in[2];
    const float* feats    = (const float*)d_in[3];
    const float* out_w    = (const float*)d_in[4];
    const float* biases   = (const float*)d_in[5];
    float* out = (float*)d_out;

    char* ws = (char*)d_ws;
    unsigned short* iw_bf  = (unsigned short*)(ws);                  //  3,145,728 B
    unsigned short* connw  = (unsigned short*)(ws + 3145728);        //    524,288 B
    unsigned short* act_a  = (unsigned short*)(ws + 3670016);        //  8,388,608 B
    unsigned short* act_b  = (unsigned short*)(ws + 12058624);       //  8,388,608 B
    float* feat_norm = (float*)(ws + 20447232);                      //    131,072 B
    float* pos_c     = (float*)(ws + 20578304);                      //      8,192 B
    float* inw       = (float*)(ws + 20586496);                      //      2,048 B
    float* biasp     = (float*)(ws + 20588544);                      //      2,048 B
    float* wout      = (float*)(ws + 20590592);                      //     20,480 B
    float* partials  = (float*)(ws + 20611072);                      // 67,108,864 B (4 x 16 MB)

    prep1<<<1, 512, 0, stream>>>(pos, feats, out_w, biases, feat_norm, pos_c, inw, biasp, wout);
    prep2<<<512, 128, 0, stream>>>(pos_c, feat_norm, connw);
    cast_pad<<<512, 256, 0, stream>>>(in_w, iw_bf, 393216L, 384000L);

    gemm1s<<<1024, 256, 0, stream>>>(x, iw_bf, partials);
    reduce_ep<<<2048, 256, 0, stream>>>(partials, inw, biasp, act_a);

    gemm2_pipe<<<512, 256, 0, stream>>>(act_a, connw, act_b, act_a);
    gemm2_pipe<<<512, 256, 0, stream>>>(act_b, connw, act_a, act_b);
    gemm2_pipe<<<512, 256, 0, stream>>>(act_a, connw, act_b, act_a);

    out_gemm<<<NBATCH/4, 256, 0, stream>>>(act_b, wout, out);
}

// Round 12
// 120.640 us; speedup vs baseline: 1.1331x; 1.1331x over previous
//
#include <hip/hip_runtime.h>
#include <stdint.h>

#define N_REAL 500
#define NPAD   512
#define K_IN   3072
#define NBATCH 8192
#define NOUT   10
#define RADIUS 20.0f
#define VOLF   100.0f

typedef __attribute__((ext_vector_type(8))) __bf16 bf16x8;
typedef __attribute__((ext_vector_type(4))) float  f32x4;
typedef __attribute__((ext_vector_type(4))) unsigned short us4;

__device__ __forceinline__ unsigned short f2bf(float f) {
    unsigned int u = __float_as_uint(f);
    u += 0x7FFFu + ((u >> 16) & 1u);           // round-to-nearest-even
    return (unsigned short)(u >> 16);
}
__device__ __forceinline__ float bf2f(unsigned short h) {
    return __uint_as_float(((unsigned int)h) << 16);
}
// HW packed f32->bf16 (RNE), 2 insts per float4
__device__ __forceinline__ uint2 cvt_pk4(float4 v) {
    uint2 r;
    asm("v_cvt_pk_bf16_f32 %0, %1, %2" : "=v"(r.x) : "v"(v.x), "v"(v.y));
    asm("v_cvt_pk_bf16_f32 %0, %1, %2" : "=v"(r.y) : "v"(v.z), "v"(v.w));
    return r;
}

#define GLOBAL_AS __attribute__((address_space(1)))
#define LDS_AS    __attribute__((address_space(3)))
__device__ __forceinline__ void glds16(const void* g, void* l) {
    __builtin_amdgcn_global_load_lds((const GLOBAL_AS void*)g, (LDS_AS void*)l, 16, 0, 0);
}

// ---------------- prep1 ----------------
__global__ void prep1(const float* __restrict__ positions,
                      const float* __restrict__ features,
                      const float* __restrict__ out_w,
                      const float* __restrict__ biases,
                      float* __restrict__ feat_norm,   // [512][64]
                      float* __restrict__ pos_c,       // [512][4]
                      float* __restrict__ inw,         // [512]
                      float* __restrict__ biasp,       // [512]
                      float* __restrict__ wout)        // [512][10]
{
    int n = threadIdx.x;  // 512 threads, 1 block
    float e_in = 0.f, e_out = 0.f;
    float px = 0.f, py = 0.f, pz = 0.f;
    if (n < N_REAL) {
        px = fminf(fmaxf(positions[n*3+0], 0.1f), VOLF - 0.1f);
        py = fminf(fmaxf(positions[n*3+1], 0.1f), VOLF - 0.1f);
        pz = fminf(fmaxf(positions[n*3+2], 0.1f), VOLF - 0.1f);
        float xn = px / VOLF;
        e_in  = expf(-2.f * xn);
        e_out = expf(2.f * (xn - 1.f));
        float ss = 0.f;
        for (int f = 0; f < 64; ++f) { float v = features[n*64+f]; ss += v*v; }
        float nm = fmaxf(sqrtf(ss), 1e-6f);
        for (int f = 0; f < 64; ++f) feat_norm[n*64+f] = features[n*64+f] / nm;
    } else {
        for (int f = 0; f < 64; ++f) feat_norm[n*64+f] = 0.f;
    }
    pos_c[n*4+0] = px; pos_c[n*4+1] = py; pos_c[n*4+2] = pz; pos_c[n*4+3] = 0.f;

    __shared__ float s_in[512], s_out[512];
    s_in[n] = e_in; s_out[n] = e_out;
    __syncthreads();
    for (int s = 256; s > 0; s >>= 1) {
        if (n < s) { s_in[n] += s_in[n+s]; s_out[n] += s_out[n+s]; }
        __syncthreads();
    }
    float sum_in  = s_in[0]  + 1e-6f;
    float sum_out = s_out[0] + 1e-6f;

    inw[n]   = (n < N_REAL) ? (e_in / sum_in) : 0.f;
    biasp[n] = (n < N_REAL) ? biases[n] : 0.f;
    float wo = (n < N_REAL) ? (e_out / sum_out) : 0.f;
    for (int o = 0; o < NOUT; ++o)
        wout[n*NOUT + o] = (n < N_REAL) ? out_w[n*NOUT + o] * wo : 0.f;
}

// ---------------- prep2 ----------------
__global__ void prep2(const float* __restrict__ pos_c,
                      const float* __restrict__ feat_norm,
                      unsigned short* __restrict__ conn_w)   // [512][512] bf16
{
    int i = blockIdx.x;   // 512
    int t = threadIdx.x;  // 128
    __shared__ float fi[64];
    __shared__ float spos[4];
    __shared__ float red[128];
    if (t < 64) fi[t] = feat_norm[i*64 + t];
    if (t < 4)  spos[t] = pos_c[i*4 + t];
    __syncthreads();

    float w[4];
    float part = 0.f;
    for (int jj = 0; jj < 4; ++jj) {
        int j = t + jj*128;
        float val = 0.f;
        if (i < N_REAL && j < N_REAL) {
            float dx = spos[0] - pos_c[j*4+0];
            float dy = spos[1] - pos_c[j*4+1];
            float dz = spos[2] - pos_c[j*4+2];
            float sq = dx*dx + dy*dy + dz*dz;
            if (sq > 0.f) {
                float dist = sqrtf(sq);
                if (dist < RADIUS) {
                    float att = expf(-dist / RADIUS);
                    float sim = 0.f;
                    const float4* fj = (const float4*)(feat_norm + j*64);
                    const float4* fi4 = (const float4*)fi;
                    #pragma unroll
                    for (int f = 0; f < 16; ++f) {
                        float4 a = fi4[f]; float4 b = fj[f];
                        sim += a.x*b.x + a.y*b.y + a.z*b.z + a.w*b.w;
                    }
                    sim = fminf(fmaxf(sim, -1.f), 1.f);
                    val = att * (0.5f + 0.5f*sim);
                }
            }
        }
        w[jj] = val; part += val;
    }
    red[t] = part;
    __syncthreads();
    for (int s = 64; s > 0; s >>= 1) {
        if (t < s) red[t] += red[t+s];
        __syncthreads();
    }
    float inv = 1.f / (red[0] + 1e-6f);
    for (int jj = 0; jj < 4; ++jj)
        conn_w[(long)i*NPAD + t + jj*128] = f2bf(w[jj] * inv);
}

// ---------------- cast/pad f32 -> bf16 ----------------
__global__ void cast_pad(const float* __restrict__ src, unsigned short* __restrict__ dst,
                         long total_q, long src_q)
{
    long i = (long)blockIdx.x * blockDim.x + threadIdx.x;
    long stride = (long)gridDim.x * blockDim.x;
    for (; i < total_q; i += stride) {
        us4 o;
        if (i < src_q) {
            float4 v = ((const float4*)src)[i];
            o[0] = f2bf(v.x); o[1] = f2bf(v.y); o[2] = f2bf(v.z); o[3] = f2bf(v.w);
        } else {
            o[0] = 0; o[1] = 0; o[2] = 0; o[3] = 0;
        }
        ((us4*)dst)[i] = o;
    }
}

// gemm1 map: 1024 blocks = 8 XCD x (16 m-panels x 4 n x 2 ks).
// 4 n-blocks + 2 ks of one m-panel co-located per XCD -> A-panel L2 reuse.
__device__ __forceinline__ void block_map_g1(int b, int& m0, int& n0, int& ks) {
    int xcd = b & 7, loc = b >> 3;          // loc 0..127
    m0 = (xcd*16 + (loc >> 3)) * 64;
    int rest = loc & 7;
    n0 = (rest & 3) * 128;
    ks = rest >> 2;
}
// 512-block map (gemm2): 128 m-panels x 4 n-quarters.
__device__ __forceinline__ void block_map_g2(int b, int& m0, int& n0) {
    int xcd = b & 7, loc = b >> 3;          // loc 0..63
    m0 = (xcd*16 + (loc >> 2)) * 64;
    n0 = (loc & 3) * 128;
}

// ======== GEMM1 split-K2: tile 64x128, BK=64, strict single-buffer loop. ========
// r4/r10's proven 20 B/cyc/CU structure (small per-iter chain, 4 blocks/CU) with
// BN=128 halving staged bytes: 1024 blocks x 24 iters x 24 KB = 590 MB total.
__global__ __launch_bounds__(256, 4)
void gemm1s(const float* __restrict__ X,            // [8192][3072] f32
            const unsigned short* __restrict__ B,   // [512][3072] bf16
            float* __restrict__ Pf)                 // [2][8192][512] f32 partials
{
    __shared__ unsigned short As[64*64];    //  8 KiB, swizzled
    __shared__ unsigned short Bs[128*64];   // 16 KiB, swizzled

    const int tid  = threadIdx.x;
    const int lane = tid & 63;
    const int wave = tid >> 6;
    int m0, n0, ks; block_map_g1(blockIdx.x, m0, n0, ks);
    const int kbase = ks * (K_IN/2);          // 0 or 1536
    const int wm = (wave >> 1) * 32;
    const int wn = (wave & 1) * 64;

    f32x4 acc[2][4];
    #pragma unroll
    for (int i = 0; i < 2; ++i)
        #pragma unroll
        for (int j = 0; j < 4; ++j)
            acc[i][j] = (f32x4){0.f,0.f,0.f,0.f};

    // A reg-staging: 64 rows x 16 float4 = 1024 f4, 4 per thread (r4 pattern)
    const float4* gA[4]; int lAo[4];
    #pragma unroll
    for (int s = 0; s < 4; ++s) {
        int f = tid + s*256;
        int row = f >> 4, c4 = f & 15;
        gA[s] = (const float4*)(X + (long)(m0 + row) * K_IN + kbase) + c4;
        lAo[s] = row*128 + ((c4*8) ^ ((row & 7) << 4));
    }
    // B: 16 KB = 4 glds16/thread, pre-swizzled global source
    const char* gB[4]; char* lB[4];
    #pragma unroll
    for (int s = 0; s < 4; ++s) {
        int o = tid*16 + s*4096;
        int row = o >> 7, d = o & 127;
        gB[s] = (const char*)B + (long)(n0 + row) * (K_IN*2) + kbase*2 + (d ^ ((row & 7) << 4));
        lB[s] = (char*)Bs + o;
    }

    for (int t = 0; t < 24; ++t) {
        __syncthreads();
        #pragma unroll
        for (int s = 0; s < 4; ++s) { glds16(gB[s], lB[s]); gB[s] += 128; }
        float4 v[4];
        #pragma unroll
        for (int s = 0; s < 4; ++s) { v[s] = gA[s][0]; gA[s] += 16; }
        #pragma unroll
        for (int s = 0; s < 4; ++s)
            *(uint2*)((char*)As + lAo[s]) = cvt_pk4(v[s]);
        asm volatile("s_waitcnt vmcnt(0) lgkmcnt(0)" ::: "memory");
        __syncthreads();

        #pragma unroll
        for (int kk = 0; kk < 2; ++kk) {
            const int cb = kk*64 + (lane >> 4) * 16;
            bf16x8 afr[2], bfr[4];
            #pragma unroll
            for (int i = 0; i < 2; ++i) {
                int r = wm + i*16 + (lane & 15);
                afr[i] = *(const bf16x8*)((const char*)As + r*128 + (cb ^ ((r & 7) << 4)));
            }
            #pragma unroll
            for (int j = 0; j < 4; ++j) {
                int r = wn + j*16 + (lane & 15);
                bfr[j] = *(const bf16x8*)((const char*)Bs + r*128 + (cb ^ ((r & 7) << 4)));
            }
            #pragma unroll
            for (int i = 0; i < 2; ++i)
                #pragma unroll
                for (int j = 0; j < 4; ++j)
                    acc[i][j] = __builtin_amdgcn_mfma_f32_16x16x32_bf16(afr[i], bfr[j], acc[i][j], 0, 0, 0);
        }
    }

    // raw f32 partial store
    float* P = Pf + (long)ks * (NBATCH * (long)NPAD);
    const int mbase = m0 + wm + (lane >> 4) * 4;
    const int nbase = n0 + wn + (lane & 15);
    #pragma unroll
    for (int j = 0; j < 4; ++j) {
        const int n = nbase + j*16;
        #pragma unroll
        for (int i = 0; i < 2; ++i)
            #pragma unroll
            for (int r = 0; r < 4; ++r) {
                const long m = mbase + i*16 + r;
                P[m*NPAD + n] = acc[i][j][r];
            }
    }
}

// ---- reduce 2 partials (fixed order) + input-gate epilogue -> act bf16 ----
__global__ __launch_bounds__(256)
void reduce_ep(const float* __restrict__ Pf,       // [2][8192][512] f32
               const float* __restrict__ inw,
               const float* __restrict__ biasp,
               unsigned short* __restrict__ act)   // [8192][512] bf16
{
    const long TOTQ = (long)NBATCH * NPAD / 4;     // 1,048,576 float4
    long i = (long)blockIdx.x * blockDim.x + threadIdx.x;
    long stride = (long)gridDim.x * blockDim.x;
    for (; i < TOTQ; i += stride) {
        float4 a = ((const float4*)Pf)[i];
        float4 b = ((const float4*)Pf)[i + TOTQ];
        int nq = (int)(i & 127);                   // (n/4) index
        float4 w  = ((const float4*)inw)[nq];
        float4 bi = ((const float4*)biasp)[nq];
        us4 o;
        o[0] = f2bf((a.x + b.x) * w.x + bi.x);
        o[1] = f2bf((a.y + b.y) * w.y + bi.y);
        o[2] = f2bf((a.z + b.z) * w.z + bi.z);
        o[3] = f2bf((a.w + b.w) * w.w + bi.w);
        ((us4*)act)[i] = o;
    }
}

// ======== GEMM2 (r8/r10-proven): BM=64, BN=128, BK=64, 3-buffer ring, depth-2. ========
__global__ __launch_bounds__(256, 4)
void gemm2_pipe(const unsigned short* __restrict__ A,      // act [8192][512] bf16
                const unsigned short* __restrict__ B,      // connw [512][512] bf16
                unsigned short* __restrict__ Cbf,          // [8192][512] bf16
                const unsigned short* __restrict__ actOld) // == A
{
    constexpr int ABUF = 8192;    // 64 x 64 bf16
    constexpr int BBUF = 16384;   // 128 x 64 bf16
    __shared__ __align__(16) char lds[3*(ABUF+BBUF)];  // 72 KB
    char* const Abase = lds;
    char* const Bbase = lds + 3*ABUF;

    const int tid  = threadIdx.x;
    const int lane = tid & 63;
    const int wave = tid >> 6;
    int m0, n0; block_map_g2(blockIdx.x, m0, n0);
    const int wm = (wave >> 1) * 32;
    const int wn = (wave & 1) * 64;

    f32x4 acc[2][4];
    #pragma unroll
    for (int i = 0; i < 2; ++i)
        #pragma unroll
        for (int j = 0; j < 4; ++j)
            acc[i][j] = (f32x4){0.f,0.f,0.f,0.f};

    const char* gB[4]; int lBo[4];
    #pragma unroll
    for (int s = 0; s < 4; ++s) {
        int o = tid*16 + s*4096;
        int row = o >> 7, d = o & 127;
        gB[s] = (const char*)B + (long)(n0 + row) * (NPAD*2) + (d ^ ((row & 7) << 4));
        lBo[s] = o;
    }
    const char* gA1[2]; int lAo1[2];
    #pragma unroll
    for (int s = 0; s < 2; ++s) {
        int o = tid*16 + s*4096;
        int row = o >> 7, d = o & 127;
        gA1[s] = (const char*)A + (long)(m0 + row) * (NPAD*2) + (d ^ ((row & 7) << 4));
        lAo1[s] = o;
    }

    const int NT = NPAD >> 6;   // 8

    // prologue: tiles 0,1 in flight
    #pragma unroll
    for (int s = 0; s < 2; ++s) { glds16(gA1[s], Abase + 0*ABUF + lAo1[s]); gA1[s] += 128; }
    #pragma unroll
    for (int s = 0; s < 4; ++s) { glds16(gB[s], Bbase + 0*BBUF + lBo[s]); gB[s] += 128; }
    #pragma unroll
    for (int s = 0; s < 2; ++s) { glds16(gA1[s], Abase + 1*ABUF + lAo1[s]); gA1[s] += 128; }
    #pragma unroll
    for (int s = 0; s < 4; ++s) { glds16(gB[s], Bbase + 1*BBUF + lBo[s]); gB[s] += 128; }

    int cur = 0;
    for (int t = 0; t < NT; ++t) {
        int fb = cur + 2; if (fb >= 3) fb -= 3;
        const bool more2 = (t + 2 < NT);
        const bool more1 = (t + 1 < NT);
        if (more2) {
            #pragma unroll
            for (int s = 0; s < 2; ++s) { glds16(gA1[s], Abase + fb*ABUF + lAo1[s]); gA1[s] += 128; }
            #pragma unroll
            for (int s = 0; s < 4; ++s) { glds16(gB[s], Bbase + fb*BBUF + lBo[s]); gB[s] += 128; }
            asm volatile("s_waitcnt vmcnt(12)" ::: "memory");
        } else if (more1) {
            asm volatile("s_waitcnt vmcnt(6)" ::: "memory");
        } else {
            asm volatile("s_waitcnt vmcnt(0)" ::: "memory");
        }
        __builtin_amdgcn_s_barrier();

        const char* Ab = Abase + cur*ABUF;
        const char* Bb = Bbase + cur*BBUF;
        #pragma unroll
        for (int kk = 0; kk < 2; ++kk) {
            const int cb = kk*64 + (lane >> 4) * 16;
            bf16x8 afr[2], bfr[4];
            #pragma unroll
            for (int i = 0; i < 2; ++i) {
                int r = wm + i*16 + (lane & 15);
                afr[i] = *(const bf16x8*)(Ab + r*128 + (cb ^ ((r & 7) << 4)));
            }
            #pragma unroll
            for (int j = 0; j < 4; ++j) {
                int r = wn + j*16 + (lane & 15);
                bfr[j] = *(const bf16x8*)(Bb + r*128 + (cb ^ ((r & 7) << 4)));
            }
            #pragma unroll
            for (int i = 0; i < 2; ++i)
                #pragma unroll
                for (int j = 0; j < 4; ++j)
                    acc[i][j] = __builtin_amdgcn_mfma_f32_16x16x32_bf16(afr[i], bfr[j], acc[i][j], 0, 0, 0);
        }
        __builtin_amdgcn_s_barrier();
        cur = (cur == 2) ? 0 : cur + 1;
    }

    const int mbase = m0 + wm + (lane >> 4) * 4;
    const int nbase = n0 + wn + (lane & 15);
    #pragma unroll
    for (int j = 0; j < 4; ++j) {
        const int n = nbase + j*16;
        #pragma unroll
        for (int i = 0; i < 2; ++i)
            #pragma unroll
            for (int r = 0; r < 4; ++r) {
                const long m = mbase + i*16 + r;
                float old = bf2f(actOld[m*NPAD + n]);
                float vv = fminf(fmaxf(old + 0.5f * acc[i][j][r], 0.f), 50.f);
                Cbf[m*NPAD + n] = f2bf(vv);
            }
    }
}

// ---------------- final projection: out[8192][10] = act @ wout ----------------
__global__ __launch_bounds__(256)
void out_gemm(const unsigned short* __restrict__ act,  // [8192][512] bf16
              const float* __restrict__ wout,          // [512][10]
              float* __restrict__ out)                 // [8192][10]
{
    __shared__ float sw[NPAD * NOUT];
    const int tid = threadIdx.x;
    for (int i = tid; i < NPAD*NOUT; i += 256) sw[i] = wout[i];
    __syncthreads();

    const int lane = tid & 63;
    const int wv   = tid >> 6;
    const int row  = blockIdx.x * 4 + wv;

    const unsigned short* ap = act + (long)row * NPAD + lane * 8;
    us4 v0 = *(const us4*)(ap);
    us4 v1 = *(const us4*)(ap + 4);

    float p[NOUT];
    #pragma unroll
    for (int o = 0; o < NOUT; ++o) p[o] = 0.f;

    const int nb = lane * 8;
    #pragma unroll
    for (int e = 0; e < 8; ++e) {
        float a = bf2f(e < 4 ? v0[e] : v1[e-4]);
        const float* wr = &sw[(nb + e) * NOUT];
        #pragma unroll
        for (int o = 0; o < NOUT; ++o) p[o] += a * wr[o];
    }
    #pragma unroll
    for (int o = 0; o < NOUT; ++o) {
        float s = p[o];
        for (int d = 32; d > 0; d >>= 1) s += __shfl_down(s, d);
        if (lane == 0) out[(long)row * NOUT + o] = s;
    }
}

extern "C" void kernel_launch(void* const* d_in, const int* in_sizes, int n_in,
                              void* d_out, int out_size, void* d_ws, size_t ws_size,
                              hipStream_t stream)
{
    const float* x        = (const float*)d_in[0];
    const float* pos      = (const float*)d_in[1];
    const float* in_w     = (const float*)d_in[2];
    const float* feats    = (const float*)d_in[3];
    const float* out_w    = (const float*)d_in[4];
    const float* biases   = (const float*)d_in[5];
    float* out = (float*)d_out;

    char* ws = (char*)d_ws;
    unsigned short* iw_bf  = (unsigned short*)(ws);                  //  3,145,728 B
    unsigned short* connw  = (unsigned short*)(ws + 3145728);        //    524,288 B
    unsigned short* act_a  = (unsigned short*)(ws + 3670016);        //  8,388,608 B
    unsigned short* act_b  = (unsigned short*)(ws + 12058624);       //  8,388,608 B
    float* feat_norm = (float*)(ws + 20447232);                      //    131,072 B
    float* pos_c     = (float*)(ws + 20578304);                      //      8,192 B
    float* inw       = (float*)(ws + 20586496);                      //      2,048 B
    float* biasp     = (float*)(ws + 20588544);                      //      2,048 B
    float* wout      = (float*)(ws + 20590592);                      //     20,480 B
    float* partials  = (float*)(ws + 20611072);                      // 33,554,432 B (2 x 16 MB)

    prep1<<<1, 512, 0, stream>>>(pos, feats, out_w, biases, feat_norm, pos_c, inw, biasp, wout);
    prep2<<<512, 128, 0, stream>>>(pos_c, feat_norm, connw);
    cast_pad<<<512, 256, 0, stream>>>(in_w, iw_bf, 393216L, 384000L);

    gemm1s<<<1024, 256, 0, stream>>>(x, iw_bf, partials);
    reduce_ep<<<2048, 256, 0, stream>>>(partials, inw, biasp, act_a);

    gemm2_pipe<<<512, 256, 0, stream>>>(act_a, connw, act_b, act_a);
    gemm2_pipe<<<512, 256, 0, stream>>>(act_b, connw, act_a, act_b);
    gemm2_pipe<<<512, 256, 0, stream>>>(act_a, connw, act_b, act_a);

    out_gemm<<<NBATCH/4, 256, 0, stream>>>(act_b, wout, out);
}